// Round 9
// baseline (171.278 us; speedup 1.0000x reference)
//
#include <hip/hip_runtime.h>

typedef short bf16x8 __attribute__((ext_vector_type(8)));   // 8 bf16 in 4 VGPRs
typedef float f32x4  __attribute__((ext_vector_type(4)));
typedef float f32x2  __attribute__((ext_vector_type(2)));
typedef int   i32x4  __attribute__((ext_vector_type(4)));
typedef unsigned int u32x2 __attribute__((ext_vector_type(2)));

#define DEV static __device__ __forceinline__
#define LOG2E 1.4426950408889634f

DEV float bfu_to_f(unsigned short s) { return __builtin_bit_cast(float, (unsigned int)s << 16); }
DEV unsigned short f_to_bf(float f) {                 // RNE fp32 -> bf16
  unsigned int u = __builtin_bit_cast(unsigned int, f);
  u += 0x7fffu + ((u >> 16) & 1u);
  return (unsigned short)(u >> 16);
}
DEV unsigned int pack_bf_rne(float lo, float hi) {
  return (unsigned int)f_to_bf(lo) | ((unsigned int)f_to_bf(hi) << 16);
}
// bf16-pair unpack (lo/hi 16 bits of a u32 -> f32)
DEV float fplo(int u) { return __builtin_bit_cast(float, (unsigned int)u << 16); }
DEV float fphi(int u) { return __builtin_bit_cast(float, (unsigned int)u & 0xffff0000u); }
// guaranteed-native exp2 (single v_exp_f32)
DEV float nexp2(float x) {
#if __has_builtin(__builtin_amdgcn_exp2f)
  return __builtin_amdgcn_exp2f(x);
#else
  return exp2f(x);
#endif
}
// fp8 e4m3 pack/unpack (OCP on gfx950). Selector must be an ICE -> template param.
template<bool HI> DEV unsigned int pk_fp8(float a, float b, unsigned int old) {
  return __builtin_amdgcn_cvt_pk_fp8_f32(a, b, old, HI);
}
template<int W> DEV f32x2 upk_fp8(unsigned int w) {
  auto r = __builtin_amdgcn_cvt_pk_f32_fp8(w, W);
  f32x2 o; o[0] = r[0]; o[1] = r[1]; return o;
}

// dtype discriminator: adj[0][0] == 1.0 exactly. fp32 word0 == 0x3F800000;
// bf16 word0 low halfword = 0x3F80 != 0 -> never equal.
DEV bool detect_f32(const void* adj) { return ((const float*)adj)[0] == 1.0f; }

template<bool F32> DEV float ldS(const void* p, size_t i) {
  if constexpr (F32) return ((const float*)p)[i];
  else               return bfu_to_f(((const unsigned short*)p)[i]);
}
template<bool F32> DEV void ld8f(const void* p, size_t i, float* o) {
  if constexpr (F32) {
    const float* f = (const float*)p + i;
    f32x4 a = *(const f32x4*)f, b = *(const f32x4*)(f + 4);
    o[0]=a[0]; o[1]=a[1]; o[2]=a[2]; o[3]=a[3];
    o[4]=b[0]; o[5]=b[1]; o[6]=b[2]; o[7]=b[3];
  } else {
    i32x4 w = *(const i32x4*)((const unsigned short*)p + i);
#pragma unroll
    for (int k = 0; k < 4; ++k) {
      unsigned int u = (unsigned int)w[k];
      o[2*k]   = __builtin_bit_cast(float, u << 16);
      o[2*k+1] = __builtin_bit_cast(float, u & 0xffff0000u);
    }
  }
}
template<bool F32> DEV bf16x8 ldfrag(const void* p, size_t i) {
  if constexpr (F32) {
    float o[8]; ld8f<true>(p, i, o);
    union { bf16x8 v; unsigned short u[8]; } r;
#pragma unroll
    for (int k = 0; k < 8; ++k) r.u[k] = f_to_bf(o[k]);
    return r.v;
  } else {
    return __builtin_bit_cast(bf16x8, *(const i32x4*)((const unsigned short*)p + i));
  }
}

// Fragment order for a 16x32 fp8 MFMA operand tile: lane l holds elements
// [row = l&15][k-col = (l>>4)*8 .. +7] at byte offset l*8. One tile = 512 B.
// A wave's 8B load at base + lane*8 is perfectly coalesced (512 B sequential).

// ---------------- Kernel 0: adj -> fp8 e4m3 in fragment-tile order ----------------
// Tile T = it*64 + jt (it: 128 i-tiles, jt: 64 j-tiles). 4 waves/block, 1 tile/wave.
__global__ __launch_bounds__(256) void k_prep(const void* __restrict__ adj,
                                              unsigned char* __restrict__ adjF) {
  const int tid = threadIdx.x, lane = tid & 63, w = tid >> 6;
  const int T = blockIdx.x * 4 + w;                  // 0..8191
  const int it = T >> 6, jt = T & 63;
  const int m = lane & 15, q = lane >> 4;
  const size_t src = (size_t)(it * 16 + m) * 2048 + jt * 32 + q * 8;
  float f[8];
  if (detect_f32(adj)) ld8f<true>(adj, src, f);
  else                 ld8f<false>(adj, src, f);
  u32x2 o;
  o[0] = pk_fp8<true>(f[2], f[3], pk_fp8<false>(f[0], f[1], 0u));
  o[1] = pk_fp8<true>(f[6], f[7], pk_fp8<false>(f[4], f[5], 0u));
  *(u32x2*)(adjF + (size_t)T * 512 + lane * 8) = o;
}

// ---------------- Kernel 1: vtF = (x@W^T)^T in A-fragment order, fp8 ----------------
// vtF tile index: ((bh*2 + dh)*64 + jt); element (d,j): lane = ((j>>3)&3)*16 + (d&15).
template<bool F32> DEV void k_h_body(const void* __restrict__ x, const void* __restrict__ W,
                                     unsigned char* __restrict__ vtF,
                                     unsigned short (&t_s)[16][136]) {
  const int tid = threadIdx.x, lane = tid & 63, wave = tid >> 6;
  const int nt = blockIdx.x >> 3, ct = blockIdx.x & 7;    // 128 nt x 8 ct
  const int m = lane & 15, q = lane >> 4;
  bf16x8 wf[4];
#pragma unroll
  for (int k = 0; k < 4; ++k)
    wf[k] = ldfrag<F32>(W, (size_t)(ct * 16 + m) * 128 + q * 8 + k * 32);
#pragma unroll
  for (int s = 0; s < 2; ++s) {
    const int nsub = wave * 2 + s;
    const size_t xr = (size_t)(nt * 128 + nsub * 16 + m) * 128 + q * 8;
    f32x4 acc = {0.f, 0.f, 0.f, 0.f};
#pragma unroll
    for (int k = 0; k < 4; ++k)
      acc = __builtin_amdgcn_mfma_f32_16x16x32_bf16(ldfrag<F32>(x, xr + k * 32), wf[k],
                                                    acc, 0, 0, 0);
    u32x2 w2; w2[0] = pack_bf_rne(acc[0], acc[1]); w2[1] = pack_bf_rne(acc[2], acc[3]);
    *(u32x2*)&t_s[m][nsub * 16 + q * 4] = w2;
  }
  __syncthreads();
  const int row = tid >> 4, c8 = tid & 15;
  const int chg = ct * 16 + row, hh = chg >> 5, dloc = chg & 31;
  const int ng = nt * 128 + c8 * 8, b = ng >> 11, nl = ng & 2047;
  i32x4 v = *(const i32x4*)&t_s[row][c8 * 8];       // 8 bf16
  float f[8];
#pragma unroll
  for (int k = 0; k < 4; ++k) {
    unsigned int u = (unsigned int)v[k];
    f[2*k]   = __builtin_bit_cast(float, u << 16);
    f[2*k+1] = __builtin_bit_cast(float, u & 0xffff0000u);
  }
  u32x2 o;
  o[0] = pk_fp8<true>(f[2], f[3], pk_fp8<false>(f[0], f[1], 0u));
  o[1] = pk_fp8<true>(f[6], f[7], pk_fp8<false>(f[4], f[5], 0u));
  const int bh_ = b * 4 + hh;
  const size_t byte = ((size_t)(bh_ * 2 + (dloc >> 4)) * 64 + (nl >> 5)) * 512
                    + (((nl >> 3) & 3) * 16 + (dloc & 15)) * 8;
  *(u32x2*)(vtF + byte) = o;
}
__global__ __launch_bounds__(256) void k_h(const void* x, const void* W,
                                           unsigned char* vtF, const void* adj) {
  __shared__ __align__(16) unsigned short t_s[16][136];   // shared across both instantiations
  if (detect_f32(adj)) k_h_body<true>(x, W, vtF, t_s); else k_h_body<false>(x, W, vtF, t_s);
}

// ---------------- Kernel 1b: src/dst projections -> rank-1 softmax factors ----------
// p'_ij = adj * max(F_j, R_i*H_j), R=exp(-0.8*src), F=exp(dst), H=exp(0.2*dst).
// F,H packed as one bf16 pair per j. Reads h from vtF (fragment order).
template<bool F32> DEV void k_sd_body(const unsigned char* __restrict__ vtF,
                                      const void* __restrict__ a_src, const void* __restrict__ a_dst,
                                      float* __restrict__ rv, unsigned int* __restrict__ fhv) {
  const int t = blockIdx.x * 256 + threadIdx.x;      // (bh, n), n fastest
  const int n = t & 2047, bh = t >> 11, hh = bh & 3;
  const unsigned char* colp = vtF + ((size_t)(bh * 2) * 64 + (n >> 5)) * 512
                            + ((n >> 3) & 3) * 128 + (n & 7);
  float s = 0.f, d = 0.f;
#pragma unroll
  for (int dd = 0; dd < 32; ++dd) {
    const float v = __builtin_amdgcn_cvt_f32_fp8(
                      (int)colp[(dd >> 4) * 32768 + (dd & 15) * 8], 0);
    s += v * ldS<F32>(a_src, hh * 32 + dd);
    d += v * ldS<F32>(a_dst, hh * 32 + dd);
  }
  rv[t] = nexp2(-0.8f * LOG2E * s);                  // R_i (f32)
  const float F = nexp2(LOG2E * d);                  // F_j
  const float H = nexp2(0.2f * LOG2E * d);           // H_j
  fhv[t] = pack_bf_rne(F, H);                        // lo=F, hi=H (bf16 pair)
}
__global__ __launch_bounds__(256) void k_sd(const unsigned char* vtF, const void* a_src,
                                            const void* a_dst, float* rv, unsigned int* fhv,
                                            const void* adj) {
  if (detect_f32(adj)) k_sd_body<true>(vtF, a_src, a_dst, rv, fhv);
  else                 k_sd_body<false>(vtF, a_src, a_dst, rv, fhv);
}

// ---------------- Kernel 2: fp8 streaming GAT attention, depth-2 reg pipeline --------
// r8 post-mortem: traffic halved, dur unchanged; r7 counters showed VGPR=64 (acc
// alone is 48) -> compiler kept ZERO prefetch registers: each chunk = issue loads,
// stall ~600cy on L2/L3 latency, compute ~300cy, repeat = latency-bound at <15% busy.
// This version hand-pipelines with a statically-named pA/pB PrefRegs double-buffer
// (no runtime indexing -> stays in VGPRs): loads for chunk c+1 issue BEFORE compute
// of chunk c, so one compute body (~300cy) x 4-wave interleave covers the latency.
// s_setprio(1) around MFMA triples (independent barrier-free waves = the regime where
// it measures +4-7%). ~110 VGPR -> still 4 waves/SIMD. Everything else = r8.
struct PrefRegs {
  u32x2 aw[4];     // adj fp8 fragments, 4 i-tiles (8 VGPR)
  long  a0, a1;    // V^T dh=0/1 fragments (4 VGPR)
  i32x4 u0, u1;    // F/H bf16 pairs (8 VGPR)
};

DEV void pref_load(PrefRegs& r, const unsigned char* ap, const unsigned char* vp0,
                   const unsigned char* vp1, const unsigned int* fp, int j) {
  r.a0 = *(const long*)(vp0 + j * 512);
  r.a1 = *(const long*)(vp1 + j * 512);
  r.u0 = *(const i32x4*)(fp + j * 32);
  r.u1 = *(const i32x4*)(fp + j * 32 + 4);
#pragma unroll
  for (int it = 0; it < 4; ++it)
    r.aw[it] = *(const u32x2*)(ap + it * 32768 + j * 512);
}

DEV void attn_compute(const PrefRegs& r, const f32x2 (&Ri2)[4],
                      f32x4 (&accA)[4], f32x4 (&accB)[4], f32x4 (&accD)[4]) {
  const long Aones = 0x3838383838383838L;            // 8x fp8 e4m3 1.0
  const f32x2 F0 = {fplo(r.u0[0]), fplo(r.u0[1])}, H0 = {fphi(r.u0[0]), fphi(r.u0[1])};
  const f32x2 F1 = {fplo(r.u0[2]), fplo(r.u0[3])}, H1 = {fphi(r.u0[2]), fphi(r.u0[3])};
  const f32x2 F2 = {fplo(r.u1[0]), fplo(r.u1[1])}, H2 = {fphi(r.u1[0]), fphi(r.u1[1])};
  const f32x2 F3 = {fplo(r.u1[2]), fplo(r.u1[3])}, H3 = {fphi(r.u1[2]), fphi(r.u1[3])};
#pragma unroll
  for (int it = 0; it < 4; ++it) {
    const u32x2 aw = r.aw[it];
    f32x2 av0 = upk_fp8<0>(aw[0]), av1 = upk_fp8<1>(aw[0]);
    f32x2 av2 = upk_fp8<0>(aw[1]), av3 = upk_fp8<1>(aw[1]);
    f32x2 w0 = __builtin_elementwise_max(F0, Ri2[it] * H0);        // exp(leaky)/E_i
    f32x2 w1 = __builtin_elementwise_max(F1, Ri2[it] * H1);
    f32x2 w2 = __builtin_elementwise_max(F2, Ri2[it] * H2);
    f32x2 w3 = __builtin_elementwise_max(F3, Ri2[it] * H3);
    f32x2 pv0 = av0 * w0, pv1 = av1 * w1, pv2 = av2 * w2, pv3 = av3 * w3;
    u32x2 bp;
    bp[0] = pk_fp8<true>(pv1[0], pv1[1], pk_fp8<false>(pv0[0], pv0[1], 0u));
    bp[1] = pk_fp8<true>(pv3[0], pv3[1], pk_fp8<false>(pv2[0], pv2[1], 0u));
    const long B = __builtin_bit_cast(long, bp);
    __builtin_amdgcn_s_setprio(1);
    accA[it] = __builtin_amdgcn_mfma_f32_16x16x32_fp8_fp8(r.a0,  B, accA[it], 0, 0, 0);
    accB[it] = __builtin_amdgcn_mfma_f32_16x16x32_fp8_fp8(r.a1,  B, accB[it], 0, 0, 0);
    accD[it] = __builtin_amdgcn_mfma_f32_16x16x32_fp8_fp8(Aones, B, accD[it], 0, 0, 0);
    __builtin_amdgcn_s_setprio(0);
  }
}

__global__ __launch_bounds__(256, 4) void k_attn(const unsigned char* __restrict__ adjF,
                                                 const unsigned char* __restrict__ vtF,
                                                 const float* __restrict__ rv,
                                                 const unsigned int* __restrict__ fhv,
                                                 unsigned short* __restrict__ ao) {
  __shared__ __align__(16) float red[6144];          // 24576 B epilogue scratch
  const int tid = threadIdx.x, lane = tid & 63, wave = tid >> 6;   // wave = j-quarter
  const int bh = blockIdx.x & 31, iblk = blockIdx.x >> 5;  // natural: XCD = bh%8
  const int b = bh >> 2, hh = bh & 3;
  const int m = lane & 15, q = lane >> 4;
  const int i0 = iblk * 64;
  const int jq0 = wave * 16;                         // first j-tile (of 64) for this wave

  const unsigned char* ap  = adjF + ((size_t)(iblk * 4) * 64 + jq0) * 512 + lane * 8;
  const unsigned char* vp0 = vtF + ((size_t)(bh * 2    ) * 64 + jq0) * 512 + lane * 8;
  const unsigned char* vp1 = vtF + ((size_t)(bh * 2 + 1) * 64 + jq0) * 512 + lane * 8;
  const unsigned int*  fp  = fhv + (size_t)bh * 2048 + jq0 * 32 + q * 8;

  f32x2 Ri2[4];
#pragma unroll
  for (int it = 0; it < 4; ++it) {
    const float r = rv[bh * 2048 + i0 + it * 16 + m];
    Ri2[it][0] = r; Ri2[it][1] = r;
  }

  f32x4 accA[4], accB[4], accD[4];
#pragma unroll
  for (int it = 0; it < 4; ++it) {
    accA[it] = f32x4{0.f,0.f,0.f,0.f};
    accB[it] = f32x4{0.f,0.f,0.f,0.f};
    accD[it] = f32x4{0.f,0.f,0.f,0.f};
  }

  // ---- depth-2 software pipeline: load(c+1) issued before compute(c) ----
  PrefRegs pA, pB;
  pref_load(pA, ap, vp0, vp1, fp, 0);
#pragma unroll
  for (int c = 0; c < 16; c += 2) {
    pref_load(pB, ap, vp0, vp1, fp, c + 1);          // c+1 <= 15 always
    attn_compute(pA, Ri2, accA, accB, accD);
    if (c + 2 < 16) pref_load(pA, ap, vp0, vp1, fp, c + 2);
    attn_compute(pB, Ri2, accA, accB, accD);
  }

  // ---- 2-round tree merge of the 4 j-quarter partials (r4-verified pattern) ----
  if (wave == 1 || wave == 3) {
    const int reg = (wave >> 1) * 3072;
#pragma unroll
    for (int it = 0; it < 4; ++it) {
      const int base = reg + (it * 64 + lane) * 12;
      *(f32x4*)&red[base]     = accA[it];
      *(f32x4*)&red[base + 4] = accB[it];
      red[base + 8] = accD[it][0];
    }
  }
  __syncthreads();
  if (wave == 0 || wave == 2) {
    const int reg = (wave >> 1) * 3072;
#pragma unroll
    for (int it = 0; it < 4; ++it) {
      const int base = reg + (it * 64 + lane) * 12;
      accA[it] += *(const f32x4*)&red[base];
      accB[it] += *(const f32x4*)&red[base + 4];
      accD[it][0] += red[base + 8];
    }
  }
  __syncthreads();
  if (wave == 2) {
#pragma unroll
    for (int it = 0; it < 4; ++it) {
      const int base = (it * 64 + lane) * 12;
      *(f32x4*)&red[base]     = accA[it];
      *(f32x4*)&red[base + 4] = accB[it];
      red[base + 8] = accD[it][0];
    }
  }
  __syncthreads();
  if (wave == 0) {
#pragma unroll
    for (int it = 0; it < 4; ++it) {
      const int base = (it * 64 + lane) * 12;
      const f32x4 a0 = accA[it] + *(const f32x4*)&red[base];
      const f32x4 a1 = accB[it] + *(const f32x4*)&red[base + 4];
      const float den = accD[it][0] + red[base + 8];
      const float inv = 1.f / fmaxf(den, 1e-20f);
      const int il = it * 16 + m;
      // D: col = m = i, row = q*4+r = d. Lane writes channels q*4..+3 and 16+q*4..+3.
      unsigned short* op = ao + ((size_t)(b * 2048) + i0 + il) * 128 + hh * 32 + q * 4;
      u32x2 w0, w1;
      w0[0] = pack_bf_rne(a0[0] * inv, a0[1] * inv);
      w0[1] = pack_bf_rne(a0[2] * inv, a0[3] * inv);
      w1[0] = pack_bf_rne(a1[0] * inv, a1[1] * inv);
      w1[1] = pack_bf_rne(a1[2] * inv, a1[3] * inv);
      *(u32x2*)op        = w0;
      *(u32x2*)(op + 16) = w1;
    }
  }
}

// ---------------- Kernel 3: y = LN(ao @ Wo^T + bo + x) ----------------
template<bool F32> DEV void k_out_body(const unsigned short* __restrict__ ao,
                                       const void* __restrict__ Wo, const void* __restrict__ bo,
                                       const void* __restrict__ x, const void* __restrict__ gamma,
                                       const void* __restrict__ beta, void* __restrict__ out,
                                       float (&y_s)[16][132]) {
  const int tid = threadIdx.x, lane = tid & 63, wave = tid >> 6;
  const int m = lane & 15, q = lane >> 4;
  const int rbase = blockIdx.x * 16;
  bf16x8 af[4];
#pragma unroll
  for (int k = 0; k < 4; ++k)
    af[k] = ldfrag<false>(ao, ((size_t)(rbase + m)) * 128 + q * 8 + k * 32);
  f32x4 acc[2] = {{0.f,0.f,0.f,0.f},{0.f,0.f,0.f,0.f}};
#pragma unroll
  for (int ct = 0; ct < 2; ++ct) {
    const size_t wrow = (size_t)(wave * 32 + ct * 16 + m) * 128 + q * 8;
#pragma unroll
    for (int k = 0; k < 4; ++k)
      acc[ct] = __builtin_amdgcn_mfma_f32_16x16x32_bf16(af[k], ldfrag<F32>(Wo, wrow + k * 32),
                                                        acc[ct], 0, 0, 0);
  }
#pragma unroll
  for (int ct = 0; ct < 2; ++ct) {
    const int c = wave * 32 + ct * 16 + m;
    const float bov = ldS<F32>(bo, c);
#pragma unroll
    for (int r = 0; r < 4; ++r) {
      const int row = q * 4 + r;
      y_s[row][c] = acc[ct][r] + bov + ldS<F32>(x, (size_t)(rbase + row) * 128 + c);
    }
  }
  __syncthreads();
  const int r = tid >> 4, c16 = tid & 15;
  float vals[8], sum = 0.f, sq = 0.f;
#pragma unroll
  for (int k = 0; k < 8; ++k) {
    const float v = y_s[r][c16 * 8 + k];
    vals[k] = v; sum += v; sq += v * v;
  }
#pragma unroll
  for (int msk = 1; msk < 16; msk <<= 1) {
    sum += __shfl_xor(sum, msk, 16);
    sq  += __shfl_xor(sq,  msk, 16);
  }
  const float mu  = sum * (1.f / 128.f);
  const float var = fmaxf(sq * (1.f / 128.f) - mu * mu, 0.f);
  const float rstd = rsqrtf(var + 1e-5f);
  float o[8];
#pragma unroll
  for (int k = 0; k < 8; ++k) {
    const int c = c16 * 8 + k;
    o[k] = (vals[k] - mu) * rstd * ldS<F32>(gamma, c) + ldS<F32>(beta, c);
  }
  const size_t obase = (size_t)(rbase + r) * 128 + c16 * 8;
  if constexpr (F32) {
    float* op = (float*)out + obase;
    f32x4 w0 = {o[0],o[1],o[2],o[3]}, w1 = {o[4],o[5],o[6],o[7]};
    *(f32x4*)op = w0; *(f32x4*)(op + 4) = w1;
  } else {
    union { unsigned short u[8]; i32x4 v; } ob;
#pragma unroll
    for (int k = 0; k < 8; ++k) ob.u[k] = f_to_bf(o[k]);
    *(i32x4*)((unsigned short*)out + obase) = ob.v;
  }
}
__global__ __launch_bounds__(256) void k_out(const unsigned short* ao, const void* Wo,
                                             const void* bo, const void* x, const void* gamma,
                                             const void* beta, void* out, const void* adj) {
  __shared__ __align__(16) float y_s[16][132];   // shared across both instantiations
  if (detect_f32(adj)) k_out_body<true>(ao, Wo, bo, x, gamma, beta, out, y_s);
  else                 k_out_body<false>(ao, Wo, bo, x, gamma, beta, out, y_s);
}

// ---------------- launch ----------------
extern "C" void kernel_launch(void* const* d_in, const int* in_sizes, int n_in,
                              void* d_out, int out_size, void* d_ws, size_t ws_size,
                              hipStream_t stream) {
  const void* x     = d_in[0];
  const void* adj   = d_in[1];
  const void* W     = d_in[2];
  const void* a_src = d_in[3];
  const void* a_dst = d_in[4];
  const void* Wo    = d_in[5];
  const void* bo    = d_in[6];
  const void* gamma = d_in[7];
  const void* beta  = d_in[8];

  char* ws = (char*)d_ws;
  unsigned char*  adjF  = (unsigned char*)ws;                // 4,194,304 B  fp8 adj, frag order
  unsigned char*  vtF   = (unsigned char*)(ws + 4194304);    // 2,097,152 B  fp8 V^T, frag order
  unsigned short* ao_ws = (unsigned short*)(ws + 6291456);   // 4,194,304 B  bf16 attn out
  float*          rv_ws = (float*)(ws + 10485760);           //   262,144 B  f32 R=exp(-.8 src)
  unsigned int*   fh_ws = (unsigned int*)(ws + 10747904);    //   262,144 B  packed bf16 F,H
                                                             // total 11,010,048 B

  k_prep<<<2048, 256, 0, stream>>>(adj, adjF);
  k_h   <<<1024, 256, 0, stream>>>(x, W, vtF, adj);
  k_sd  <<<256,  256, 0, stream>>>(vtF, a_src, a_dst, rv_ws, fh_ws, adj);
  k_attn<<<1024, 256, 0, stream>>>(adjF, vtF, rv_ws, fh_ws, ao_ws);
  k_out <<<1024, 256, 0, stream>>>(ao_ws, Wo, bo, x, gamma, beta, d_out, adj);
}

// Round 10
// 147.093 us; speedup vs baseline: 1.1644x; 1.1644x over previous
//
#include <hip/hip_runtime.h>

typedef short bf16x8 __attribute__((ext_vector_type(8)));   // 8 bf16 in 4 VGPRs
typedef _Float16 f16x8 __attribute__((ext_vector_type(8))); // 8 f16 in 4 VGPRs
typedef float f32x4  __attribute__((ext_vector_type(4)));
typedef float f32x2  __attribute__((ext_vector_type(2)));
typedef int   i32x4  __attribute__((ext_vector_type(4)));
typedef unsigned int u32x2 __attribute__((ext_vector_type(2)));

#define DEV static __device__ __forceinline__
#define LOG2E 1.4426950408889634f

DEV float bfu_to_f(unsigned short s) { return __builtin_bit_cast(float, (unsigned int)s << 16); }
DEV unsigned short f_to_bf(float f) {                 // RNE fp32 -> bf16
  unsigned int u = __builtin_bit_cast(unsigned int, f);
  u += 0x7fffu + ((u >> 16) & 1u);
  return (unsigned short)(u >> 16);
}
DEV unsigned int pack_bf_rne(float lo, float hi) {
  return (unsigned int)f_to_bf(lo) | ((unsigned int)f_to_bf(hi) << 16);
}
// packed f32 -> 2x f16 (single v_cvt_pkrtz_f16_f32, full rate)
DEV unsigned int pk_f16(float a, float b) {
  auto h = __builtin_amdgcn_cvt_pkrtz(a, b);
  return __builtin_bit_cast(unsigned int, h);
}
DEV unsigned short f_to_f16(float a) { return __builtin_bit_cast(unsigned short, (_Float16)a); }
// guaranteed-native exp2 (single v_exp_f32)
DEV float nexp2(float x) {
#if __has_builtin(__builtin_amdgcn_exp2f)
  return __builtin_amdgcn_exp2f(x);
#else
  return exp2f(x);
#endif
}

// dtype discriminator: adj[0][0] == 1.0 exactly. fp32 word0 == 0x3F800000;
// bf16 word0 low halfword = 0x3F80 != 0 -> never equal.
DEV bool detect_f32(const void* adj) { return ((const float*)adj)[0] == 1.0f; }

template<bool F32> DEV float ldS(const void* p, size_t i) {
  if constexpr (F32) return ((const float*)p)[i];
  else               return bfu_to_f(((const unsigned short*)p)[i]);
}
template<bool F32> DEV void ld8f(const void* p, size_t i, float* o) {
  if constexpr (F32) {
    const float* f = (const float*)p + i;
    f32x4 a = *(const f32x4*)f, b = *(const f32x4*)(f + 4);
    o[0]=a[0]; o[1]=a[1]; o[2]=a[2]; o[3]=a[3];
    o[4]=b[0]; o[5]=b[1]; o[6]=b[2]; o[7]=b[3];
  } else {
    i32x4 w = *(const i32x4*)((const unsigned short*)p + i);
#pragma unroll
    for (int k = 0; k < 4; ++k) {
      unsigned int u = (unsigned int)w[k];
      o[2*k]   = __builtin_bit_cast(float, u << 16);
      o[2*k+1] = __builtin_bit_cast(float, u & 0xffff0000u);
    }
  }
}
template<bool F32> DEV bf16x8 ldfrag(const void* p, size_t i) {
  if constexpr (F32) {
    float o[8]; ld8f<true>(p, i, o);
    union { bf16x8 v; unsigned short u[8]; } r;
#pragma unroll
    for (int k = 0; k < 8; ++k) r.u[k] = f_to_bf(o[k]);
    return r.v;
  } else {
    return __builtin_bit_cast(bf16x8, *(const i32x4*)((const unsigned short*)p + i));
  }
}

// Fragment order for a 16x32 f16 MFMA operand tile: lane l holds elements
// [row = l&15][col = (l>>4)*8 .. +7] at flat offset l*8. One tile = 512 f16 = 1 KB.
// A wave's dwordx4 load at base + lane*16B is perfectly coalesced (1 KB sequential).

// -------- Kernel 0+1 fused: adj->f16 frag order AND vtS=(x@W^T)^T frag order --------
// Blocks [0,2048): adj prep (tile T = blockIdx*4+wave). Blocks [2048,3072): k_h.
template<bool F32> DEV void prep_part(const void* __restrict__ adj,
                                      unsigned short* __restrict__ adjS, int blk) {
  const int tid = threadIdx.x, lane = tid & 63, w = tid >> 6;
  const int T = blk * 4 + w;                         // 0..8191
  const int it = T >> 6, jt = T & 63;
  const int m = lane & 15, q = lane >> 4;
  const size_t src = (size_t)(it * 16 + m) * 2048 + jt * 32 + q * 8;
  float f[8];
  ld8f<F32>(adj, src, f);
  i32x4 o;
#pragma unroll
  for (int k = 0; k < 4; ++k) o[k] = (int)pk_f16(f[2*k], f[2*k+1]);
  *(i32x4*)(adjS + (size_t)T * 512 + lane * 8) = o;
}
template<bool F32> DEV void h_part(const void* __restrict__ x, const void* __restrict__ W,
                                   unsigned short* __restrict__ vtS,
                                   unsigned short (&t_s)[16][136], int blk) {
  const int tid = threadIdx.x, lane = tid & 63, wave = tid >> 6;
  const int nt = blk >> 3, ct = blk & 7;             // 128 nt x 8 ct
  const int m = lane & 15, q = lane >> 4;
  bf16x8 wf[4];
#pragma unroll
  for (int k = 0; k < 4; ++k)
    wf[k] = ldfrag<F32>(W, (size_t)(ct * 16 + m) * 128 + q * 8 + k * 32);
#pragma unroll
  for (int s = 0; s < 2; ++s) {
    const int nsub = wave * 2 + s;
    const size_t xr = (size_t)(nt * 128 + nsub * 16 + m) * 128 + q * 8;
    f32x4 acc = {0.f, 0.f, 0.f, 0.f};
#pragma unroll
    for (int k = 0; k < 4; ++k)
      acc = __builtin_amdgcn_mfma_f32_16x16x32_bf16(ldfrag<F32>(x, xr + k * 32), wf[k],
                                                    acc, 0, 0, 0);
    u32x2 w2; w2[0] = pack_bf_rne(acc[0], acc[1]); w2[1] = pack_bf_rne(acc[2], acc[3]);
    *(u32x2*)&t_s[m][nsub * 16 + q * 4] = w2;
  }
  __syncthreads();
  const int row = tid >> 4, c8 = tid & 15;
  const int chg = ct * 16 + row, hh = chg >> 5, dloc = chg & 31;
  const int ng = nt * 128 + c8 * 8, b = ng >> 11, nl = ng & 2047;
  i32x4 v = *(const i32x4*)&t_s[row][c8 * 8];       // 8 bf16
  float f[8];
#pragma unroll
  for (int k = 0; k < 4; ++k) {
    unsigned int u = (unsigned int)v[k];
    f[2*k]   = __builtin_bit_cast(float, u << 16);
    f[2*k+1] = __builtin_bit_cast(float, u & 0xffff0000u);
  }
  i32x4 o;
#pragma unroll
  for (int k = 0; k < 4; ++k) o[k] = (int)pk_f16(f[2*k], f[2*k+1]);
  const int bh_ = b * 4 + hh;
  const size_t idx = ((size_t)(bh_ * 2 + (dloc >> 4)) * 64 + (nl >> 5)) * 512
                   + (((nl >> 3) & 3) * 16 + (dloc & 15)) * 8;
  *(i32x4*)(vtS + idx) = o;
}
__global__ __launch_bounds__(256) void k_pre(const void* adj, const void* x, const void* W,
                                             unsigned short* adjS, unsigned short* vtS) {
  __shared__ __align__(16) unsigned short t_s[16][136];
  const bool f32 = detect_f32(adj);
  if (blockIdx.x < 2048) {
    if (f32) prep_part<true>(adj, adjS, blockIdx.x);
    else     prep_part<false>(adj, adjS, blockIdx.x);
  } else {
    if (f32) h_part<true>(x, W, vtS, t_s, blockIdx.x - 2048);
    else     h_part<false>(x, W, vtS, t_s, blockIdx.x - 2048);
  }
}

// ---------------- Kernel 1b: src/dst projections -> rank-1 softmax factors ----------
// p'_ij = adj * max(F_j, R_i*H_j), R=exp(-0.8*src), F=exp(dst), H=exp(0.2*dst).
template<bool F32> DEV void k_sd_body(const unsigned short* __restrict__ vtS,
                                      const void* __restrict__ a_src, const void* __restrict__ a_dst,
                                      unsigned int* __restrict__ rvh,
                                      unsigned short* __restrict__ Fh,
                                      unsigned short* __restrict__ Hh) {
  const int t = blockIdx.x * 256 + threadIdx.x;      // (bh, n), n fastest
  const int n = t & 2047, bh = t >> 11, hh = bh & 3;
  const unsigned short* colp = vtS + ((size_t)(bh * 2) * 64 + (n >> 5)) * 512
                             + ((n >> 3) & 3) * 128 + (n & 7);
  float s = 0.f, d = 0.f;
#pragma unroll
  for (int dd = 0; dd < 32; ++dd) {
    const float v = (float)__builtin_bit_cast(_Float16,
                      colp[(dd >> 4) * 32768 + (dd & 15) * 8]);
    s += v * ldS<F32>(a_src, hh * 32 + dd);
    d += v * ldS<F32>(a_dst, hh * 32 + dd);
  }
  const float R = nexp2(-0.8f * LOG2E * s);
  const float F = nexp2(LOG2E * d);
  const float H = nexp2(0.2f * LOG2E * d);
  rvh[t] = pk_f16(R, R);                             // broadcast f16 pair
  Fh[t] = f_to_f16(F);
  Hh[t] = f_to_f16(H);
}
__global__ __launch_bounds__(256) void k_sd(const unsigned short* vtS, const void* a_src,
                                            const void* a_dst, unsigned int* rvh,
                                            unsigned short* Fh, unsigned short* Hh,
                                            const void* adj) {
  if (detect_f32(adj)) k_sd_body<true>(vtS, a_src, a_dst, rvh, Fh, Hh);
  else                 k_sd_body<false>(vtS, a_src, a_dst, rvh, Fh, Hh);
}

// ---------------- Kernel 2: f16 streaming GAT attention, depth-2 reg pipeline --------
// r9 post-mortem: the pipeline test spilled (acc 48 + pref 40 > 128-VGPR budget at
// 4 waves/SIMD; WRITE_SIZE 67MB = scratch). This version = r6's verified 38us
// structure (f16, 2 i-tiles/wave, frag-order streams, no LDS/barriers in main loop)
// + a depth-2 prefetch that FITS: Pref = 6 x i32x4 = 24 VGPR/buffer; total ~100.
// Loads for chunk c+1 issue before compute of chunk c; 4 waves/SIMD interleave covers
// L2/L3 latency. s_setprio(1) around MFMA triples (barrier-free independent waves).
struct Pref {
  i32x4 a0, a1;    // adj f16 fragments, i-tiles 0/1
  i32x4 v0, v1;    // V^T dh=0/1 fragments
  i32x4 ff, fh;    // F, H f16 rows
};

DEV void pload(Pref& p, const unsigned short* ap0, const unsigned short* ap1,
               const unsigned short* vp0, const unsigned short* vp1,
               const unsigned short* fpF, const unsigned short* fpH, int j) {
  p.a0 = *(const i32x4*)(ap0 + j * 512);
  p.a1 = *(const i32x4*)(ap1 + j * 512);
  p.v0 = *(const i32x4*)(vp0 + j * 512);
  p.v1 = *(const i32x4*)(vp1 + j * 512);
  p.ff = *(const i32x4*)(fpF + j * 32);
  p.fh = *(const i32x4*)(fpH + j * 32);
}

DEV void pcompute(const Pref& p, const f16x8 R80, const f16x8 R81, const f16x8 ONE8,
                  f32x4 (&accA)[2], f32x4 (&accB)[2], f32x4 (&accD)[2]) {
  const f16x8 F8 = __builtin_bit_cast(f16x8, p.ff);
  const f16x8 H8 = __builtin_bit_cast(f16x8, p.fh);
  const f16x8 A0 = __builtin_bit_cast(f16x8, p.v0);
  const f16x8 A1 = __builtin_bit_cast(f16x8, p.v1);
  const f16x8 w0 = __builtin_elementwise_max(F8, R80 * H8);   // exp(leaky)/E_i
  const f16x8 p0 = __builtin_bit_cast(f16x8, p.a0) * w0;
  __builtin_amdgcn_s_setprio(1);
  accA[0] = __builtin_amdgcn_mfma_f32_16x16x32_f16(A0,   p0, accA[0], 0, 0, 0);
  accB[0] = __builtin_amdgcn_mfma_f32_16x16x32_f16(A1,   p0, accB[0], 0, 0, 0);
  accD[0] = __builtin_amdgcn_mfma_f32_16x16x32_f16(ONE8, p0, accD[0], 0, 0, 0);
  __builtin_amdgcn_s_setprio(0);
  const f16x8 w1 = __builtin_elementwise_max(F8, R81 * H8);
  const f16x8 p1 = __builtin_bit_cast(f16x8, p.a1) * w1;
  __builtin_amdgcn_s_setprio(1);
  accA[1] = __builtin_amdgcn_mfma_f32_16x16x32_f16(A0,   p1, accA[1], 0, 0, 0);
  accB[1] = __builtin_amdgcn_mfma_f32_16x16x32_f16(A1,   p1, accB[1], 0, 0, 0);
  accD[1] = __builtin_amdgcn_mfma_f32_16x16x32_f16(ONE8, p1, accD[1], 0, 0, 0);
  __builtin_amdgcn_s_setprio(0);
}

__global__ __launch_bounds__(256, 4) void k_attn(const unsigned short* __restrict__ adjS,
                                                 const unsigned short* __restrict__ vtS,
                                                 const unsigned int* __restrict__ rvh,
                                                 const unsigned short* __restrict__ Fh,
                                                 const unsigned short* __restrict__ Hh,
                                                 unsigned short* __restrict__ ao) {
  __shared__ __align__(16) float red[3072];          // 12288 B epilogue scratch
  const int tid = threadIdx.x, lane = tid & 63, wave = tid >> 6;   // wave = j-quarter
  const int bh = blockIdx.x & 31, iblk = blockIdx.x >> 5;  // natural: XCD = bh%8
  const int b = bh >> 2, hh = bh & 3;
  const int m = lane & 15, q = lane >> 4;
  const int i0 = iblk * 32;
  const int jq0 = wave * 16;                         // first j-tile (of 64) for this wave

  const unsigned short* ap0 = adjS + ((size_t)(iblk * 2    ) * 64 + jq0) * 512 + lane * 8;
  const unsigned short* ap1 = adjS + ((size_t)(iblk * 2 + 1) * 64 + jq0) * 512 + lane * 8;
  const unsigned short* vp0 = vtS + ((size_t)(bh * 2    ) * 64 + jq0) * 512 + lane * 8;
  const unsigned short* vp1 = vtS + ((size_t)(bh * 2 + 1) * 64 + jq0) * 512 + lane * 8;
  const unsigned short* fpF = Fh + (size_t)bh * 2048 + jq0 * 32 + q * 8;
  const unsigned short* fpH = Hh + (size_t)bh * 2048 + jq0 * 32 + q * 8;

  const unsigned int r0 = rvh[bh * 2048 + i0 + m];
  const unsigned int r1 = rvh[bh * 2048 + i0 + 16 + m];
  const i32x4 rb0 = {(int)r0, (int)r0, (int)r0, (int)r0};
  const i32x4 rb1 = {(int)r1, (int)r1, (int)r1, (int)r1};
  const f16x8 R80 = __builtin_bit_cast(f16x8, rb0);
  const f16x8 R81 = __builtin_bit_cast(f16x8, rb1);
  const i32x4 onev = {0x3C003C00, 0x3C003C00, 0x3C003C00, 0x3C003C00};
  const f16x8 ONE8 = __builtin_bit_cast(f16x8, onev);  // 8x f16 1.0

  f32x4 accA[2], accB[2], accD[2];
#pragma unroll
  for (int it = 0; it < 2; ++it) {
    accA[it] = f32x4{0.f,0.f,0.f,0.f};
    accB[it] = f32x4{0.f,0.f,0.f,0.f};
    accD[it] = f32x4{0.f,0.f,0.f,0.f};
  }

  // ---- depth-2 software pipeline: load(c+1) issued before compute(c) ----
  Pref pA, pB;
  pload(pA, ap0, ap1, vp0, vp1, fpF, fpH, 0);
#pragma unroll
  for (int c = 0; c < 16; c += 2) {
    pload(pB, ap0, ap1, vp0, vp1, fpF, fpH, c + 1);
    pcompute(pA, R80, R81, ONE8, accA, accB, accD);
    if (c + 2 < 16) pload(pA, ap0, ap1, vp0, vp1, fpF, fpH, c + 2);
    pcompute(pB, R80, R81, ONE8, accA, accB, accD);
  }

  // ---- 2-round tree merge of the 4 j-quarter partials (r6-verified pattern) ----
  if (wave == 1 || wave == 3) {
    const int reg = (wave >> 1) * 1536;
#pragma unroll
    for (int it = 0; it < 2; ++it) {
      const int base = reg + (it * 64 + lane) * 12;
      *(f32x4*)&red[base]     = accA[it];
      *(f32x4*)&red[base + 4] = accB[it];
      red[base + 8] = accD[it][0];
    }
  }
  __syncthreads();
  if (wave == 0 || wave == 2) {
    const int reg = (wave >> 1) * 1536;
#pragma unroll
    for (int it = 0; it < 2; ++it) {
      const int base = reg + (it * 64 + lane) * 12;
      accA[it] += *(const f32x4*)&red[base];
      accB[it] += *(const f32x4*)&red[base + 4];
      accD[it][0] += red[base + 8];
    }
  }
  __syncthreads();
  if (wave == 2) {
#pragma unroll
    for (int it = 0; it < 2; ++it) {
      const int base = (it * 64 + lane) * 12;
      *(f32x4*)&red[base]     = accA[it];
      *(f32x4*)&red[base + 4] = accB[it];
      red[base + 8] = accD[it][0];
    }
  }
  __syncthreads();
  if (wave == 0) {
#pragma unroll
    for (int it = 0; it < 2; ++it) {
      const int base = (it * 64 + lane) * 12;
      const f32x4 a0 = accA[it] + *(const f32x4*)&red[base];
      const f32x4 a1 = accB[it] + *(const f32x4*)&red[base + 4];
      const float den = accD[it][0] + red[base + 8];
      const float inv = 1.f / fmaxf(den, 1e-20f);
      const int il = it * 16 + m;
      // D: col = m = i, row = q*4+r = d. Lane writes channels q*4..+3 and 16+q*4..+3.
      unsigned short* op = ao + ((size_t)(b * 2048) + i0 + il) * 128 + hh * 32 + q * 4;
      u32x2 w0, w1;
      w0[0] = pack_bf_rne(a0[0] * inv, a0[1] * inv);
      w0[1] = pack_bf_rne(a0[2] * inv, a0[3] * inv);
      w1[0] = pack_bf_rne(a1[0] * inv, a1[1] * inv);
      w1[1] = pack_bf_rne(a1[2] * inv, a1[3] * inv);
      *(u32x2*)op        = w0;
      *(u32x2*)(op + 16) = w1;
    }
  }
}

// ---------------- Kernel 3: y = LN(ao @ Wo^T + bo + x) ----------------
template<bool F32> DEV void k_out_body(const unsigned short* __restrict__ ao,
                                       const void* __restrict__ Wo, const void* __restrict__ bo,
                                       const void* __restrict__ x, const void* __restrict__ gamma,
                                       const void* __restrict__ beta, void* __restrict__ out,
                                       float (&y_s)[16][132]) {
  const int tid = threadIdx.x, lane = tid & 63, wave = tid >> 6;
  const int m = lane & 15, q = lane >> 4;
  const int rbase = blockIdx.x * 16;
  bf16x8 af[4];
#pragma unroll
  for (int k = 0; k < 4; ++k)
    af[k] = ldfrag<false>(ao, ((size_t)(rbase + m)) * 128 + q * 8 + k * 32);
  f32x4 acc[2] = {{0.f,0.f,0.f,0.f},{0.f,0.f,0.f,0.f}};
#pragma unroll
  for (int ct = 0; ct < 2; ++ct) {
    const size_t wrow = (size_t)(wave * 32 + ct * 16 + m) * 128 + q * 8;
#pragma unroll
    for (int k = 0; k < 4; ++k)
      acc[ct] = __builtin_amdgcn_mfma_f32_16x16x32_bf16(af[k], ldfrag<F32>(Wo, wrow + k * 32),
                                                        acc[ct], 0, 0, 0);
  }
#pragma unroll
  for (int ct = 0; ct < 2; ++ct) {
    const int c = wave * 32 + ct * 16 + m;
    const float bov = ldS<F32>(bo, c);
#pragma unroll
    for (int r = 0; r < 4; ++r) {
      const int row = q * 4 + r;
      y_s[row][c] = acc[ct][r] + bov + ldS<F32>(x, (size_t)(rbase + row) * 128 + c);
    }
  }
  __syncthreads();
  const int r = tid >> 4, c16 = tid & 15;
  float vals[8], sum = 0.f, sq = 0.f;
#pragma unroll
  for (int k = 0; k < 8; ++k) {
    const float v = y_s[r][c16 * 8 + k];
    vals[k] = v; sum += v; sq += v * v;
  }
#pragma unroll
  for (int msk = 1; msk < 16; msk <<= 1) {
    sum += __shfl_xor(sum, msk, 16);
    sq  += __shfl_xor(sq,  msk, 16);
  }
  const float mu  = sum * (1.f / 128.f);
  const float var = fmaxf(sq * (1.f / 128.f) - mu * mu, 0.f);
  const float rstd = rsqrtf(var + 1e-5f);
  float o[8];
#pragma unroll
  for (int k = 0; k < 8; ++k) {
    const int c = c16 * 8 + k;
    o[k] = (vals[k] - mu) * rstd * ldS<F32>(gamma, c) + ldS<F32>(beta, c);
  }
  const size_t obase = (size_t)(rbase + r) * 128 + c16 * 8;
  if constexpr (F32) {
    float* op = (float*)out + obase;
    f32x4 w0 = {o[0],o[1],o[2],o[3]}, w1 = {o[4],o[5],o[6],o[7]};
    *(f32x4*)op = w0; *(f32x4*)(op + 4) = w1;
  } else {
    union { unsigned short u[8]; i32x4 v; } ob;
#pragma unroll
    for (int k = 0; k < 8; ++k) ob.u[k] = f_to_bf(o[k]);
    *(i32x4*)((unsigned short*)out + obase) = ob.v;
  }
}
__global__ __launch_bounds__(256) void k_out(const unsigned short* ao, const void* Wo,
                                             const void* bo, const void* x, const void* gamma,
                                             const void* beta, void* out, const void* adj) {
  __shared__ __align__(16) float y_s[16][132];   // shared across both instantiations
  if (detect_f32(adj)) k_out_body<true>(ao, Wo, bo, x, gamma, beta, out, y_s);
  else                 k_out_body<false>(ao, Wo, bo, x, gamma, beta, out, y_s);
}

// ---------------- launch ----------------
extern "C" void kernel_launch(void* const* d_in, const int* in_sizes, int n_in,
                              void* d_out, int out_size, void* d_ws, size_t ws_size,
                              hipStream_t stream) {
  const void* x     = d_in[0];
  const void* adj   = d_in[1];
  const void* W     = d_in[2];
  const void* a_src = d_in[3];
  const void* a_dst = d_in[4];
  const void* Wo    = d_in[5];
  const void* bo    = d_in[6];
  const void* gamma = d_in[7];
  const void* beta  = d_in[8];

  char* ws = (char*)d_ws;
  unsigned short* adjS  = (unsigned short*)ws;               // 8,388,608 B  f16 adj, frag order
  unsigned short* vtS   = (unsigned short*)(ws + 8388608);   // 4,194,304 B  f16 V^T, frag order
  unsigned short* ao_ws = (unsigned short*)(ws + 12582912);  // 4,194,304 B  bf16 attn out
  unsigned int*   rvh   = (unsigned int*)(ws + 16777216);    //   262,144 B  f16 pair (R,R)
  unsigned short* Fh    = (unsigned short*)(ws + 17039360);  //   131,072 B  f16 F
  unsigned short* Hh    = (unsigned short*)(ws + 17170432);  //   131,072 B  f16 H
                                                             // total 17,301,504 B

  k_pre <<<3072, 256, 0, stream>>>(adj, x, W, adjS, vtS);
  k_sd  <<<256,  256, 0, stream>>>(vtS, a_src, a_dst, rvh, Fh, Hh, adj);
  k_attn<<<2048, 256, 0, stream>>>(adjS, vtS, rvh, Fh, Hh, ao_ws);
  k_out <<<1024, 256, 0, stream>>>(ao_ws, Wo, bo, x, gamma, beta, d_out, adj);
}

// Round 11
// 146.417 us; speedup vs baseline: 1.1698x; 1.0046x over previous
//
#include <hip/hip_runtime.h>

typedef short bf16x8 __attribute__((ext_vector_type(8)));   // 8 bf16 in 4 VGPRs
typedef _Float16 f16x8 __attribute__((ext_vector_type(8))); // 8 f16 in 4 VGPRs
typedef float f32x4  __attribute__((ext_vector_type(4)));
typedef float f32x2  __attribute__((ext_vector_type(2)));
typedef int   i32x4  __attribute__((ext_vector_type(4)));
typedef unsigned int u32x2 __attribute__((ext_vector_type(2)));

#define DEV static __device__ __forceinline__
#define LOG2E 1.4426950408889634f

DEV float bfu_to_f(unsigned short s) { return __builtin_bit_cast(float, (unsigned int)s << 16); }
DEV unsigned short f_to_bf(float f) {                 // RNE fp32 -> bf16
  unsigned int u = __builtin_bit_cast(unsigned int, f);
  u += 0x7fffu + ((u >> 16) & 1u);
  return (unsigned short)(u >> 16);
}
DEV unsigned int pack_bf_rne(float lo, float hi) {
  return (unsigned int)f_to_bf(lo) | ((unsigned int)f_to_bf(hi) << 16);
}
// packed f32 -> 2x f16 (single v_cvt_pkrtz_f16_f32, full rate)
DEV unsigned int pk_f16(float a, float b) {
  auto h = __builtin_amdgcn_cvt_pkrtz(a, b);
  return __builtin_bit_cast(unsigned int, h);
}
DEV unsigned short f_to_f16(float a) { return __builtin_bit_cast(unsigned short, (_Float16)a); }
// guaranteed-native exp2 (single v_exp_f32)
DEV float nexp2(float x) {
#if __has_builtin(__builtin_amdgcn_exp2f)
  return __builtin_amdgcn_exp2f(x);
#else
  return exp2f(x);
#endif
}

// dtype discriminator: adj[0][0] == 1.0 exactly. fp32 word0 == 0x3F800000;
// bf16 word0 low halfword = 0x3F80 != 0 -> never equal.
DEV bool detect_f32(const void* adj) { return ((const float*)adj)[0] == 1.0f; }

template<bool F32> DEV float ldS(const void* p, size_t i) {
  if constexpr (F32) return ((const float*)p)[i];
  else               return bfu_to_f(((const unsigned short*)p)[i]);
}
template<bool F32> DEV void ld8f(const void* p, size_t i, float* o) {
  if constexpr (F32) {
    const float* f = (const float*)p + i;
    f32x4 a = *(const f32x4*)f, b = *(const f32x4*)(f + 4);
    o[0]=a[0]; o[1]=a[1]; o[2]=a[2]; o[3]=a[3];
    o[4]=b[0]; o[5]=b[1]; o[6]=b[2]; o[7]=b[3];
  } else {
    i32x4 w = *(const i32x4*)((const unsigned short*)p + i);
#pragma unroll
    for (int k = 0; k < 4; ++k) {
      unsigned int u = (unsigned int)w[k];
      o[2*k]   = __builtin_bit_cast(float, u << 16);
      o[2*k+1] = __builtin_bit_cast(float, u & 0xffff0000u);
    }
  }
}
template<bool F32> DEV bf16x8 ldfrag(const void* p, size_t i) {
  if constexpr (F32) {
    float o[8]; ld8f<true>(p, i, o);
    union { bf16x8 v; unsigned short u[8]; } r;
#pragma unroll
    for (int k = 0; k < 8; ++k) r.u[k] = f_to_bf(o[k]);
    return r.v;
  } else {
    return __builtin_bit_cast(bf16x8, *(const i32x4*)((const unsigned short*)p + i));
  }
}

// Fragment order for a 16x32 f16 MFMA operand tile: lane l holds elements
// [row = l&15][col = (l>>4)*8 .. +7] at flat offset l*8. One tile = 512 f16 = 1 KB.
// A wave's dwordx4 load at base + lane*16B is perfectly coalesced (1 KB sequential).

// -------- Kernel 0+1 fused: adj->f16 frag order AND vtS=(x@W^T)^T frag order --------
// Blocks [0,2048): adj prep (tile T = blockIdx*4+wave). Blocks [2048,3072): k_h.
template<bool F32> DEV void prep_part(const void* __restrict__ adj,
                                      unsigned short* __restrict__ adjS, int blk) {
  const int tid = threadIdx.x, lane = tid & 63, w = tid >> 6;
  const int T = blk * 4 + w;                         // 0..8191
  const int it = T >> 6, jt = T & 63;
  const int m = lane & 15, q = lane >> 4;
  const size_t src = (size_t)(it * 16 + m) * 2048 + jt * 32 + q * 8;
  float f[8];
  ld8f<F32>(adj, src, f);
  i32x4 o;
#pragma unroll
  for (int k = 0; k < 4; ++k) o[k] = (int)pk_f16(f[2*k], f[2*k+1]);
  *(i32x4*)(adjS + (size_t)T * 512 + lane * 8) = o;
}
template<bool F32> DEV void h_part(const void* __restrict__ x, const void* __restrict__ W,
                                   unsigned short* __restrict__ vtS,
                                   unsigned short (&t_s)[16][136], int blk) {
  const int tid = threadIdx.x, lane = tid & 63, wave = tid >> 6;
  const int nt = blk >> 3, ct = blk & 7;             // 128 nt x 8 ct
  const int m = lane & 15, q = lane >> 4;
  bf16x8 wf[4];
#pragma unroll
  for (int k = 0; k < 4; ++k)
    wf[k] = ldfrag<F32>(W, (size_t)(ct * 16 + m) * 128 + q * 8 + k * 32);
#pragma unroll
  for (int s = 0; s < 2; ++s) {
    const int nsub = wave * 2 + s;
    const size_t xr = (size_t)(nt * 128 + nsub * 16 + m) * 128 + q * 8;
    f32x4 acc = {0.f, 0.f, 0.f, 0.f};
#pragma unroll
    for (int k = 0; k < 4; ++k)
      acc = __builtin_amdgcn_mfma_f32_16x16x32_bf16(ldfrag<F32>(x, xr + k * 32), wf[k],
                                                    acc, 0, 0, 0);
    u32x2 w2; w2[0] = pack_bf_rne(acc[0], acc[1]); w2[1] = pack_bf_rne(acc[2], acc[3]);
    *(u32x2*)&t_s[m][nsub * 16 + q * 4] = w2;
  }
  __syncthreads();
  const int row = tid >> 4, c8 = tid & 15;
  const int chg = ct * 16 + row, hh = chg >> 5, dloc = chg & 31;
  const int ng = nt * 128 + c8 * 8, b = ng >> 11, nl = ng & 2047;
  i32x4 v = *(const i32x4*)&t_s[row][c8 * 8];       // 8 bf16
  float f[8];
#pragma unroll
  for (int k = 0; k < 4; ++k) {
    unsigned int u = (unsigned int)v[k];
    f[2*k]   = __builtin_bit_cast(float, u << 16);
    f[2*k+1] = __builtin_bit_cast(float, u & 0xffff0000u);
  }
  i32x4 o;
#pragma unroll
  for (int k = 0; k < 4; ++k) o[k] = (int)pk_f16(f[2*k], f[2*k+1]);
  const int bh_ = b * 4 + hh;
  const size_t idx = ((size_t)(bh_ * 2 + (dloc >> 4)) * 64 + (nl >> 5)) * 512
                   + (((nl >> 3) & 3) * 16 + (dloc & 15)) * 8;
  *(i32x4*)(vtS + idx) = o;
}
__global__ __launch_bounds__(256) void k_pre(const void* adj, const void* x, const void* W,
                                             unsigned short* adjS, unsigned short* vtS) {
  __shared__ __align__(16) unsigned short t_s[16][136];
  const bool f32 = detect_f32(adj);
  if (blockIdx.x < 2048) {
    if (f32) prep_part<true>(adj, adjS, blockIdx.x);
    else     prep_part<false>(adj, adjS, blockIdx.x);
  } else {
    if (f32) h_part<true>(x, W, vtS, t_s, blockIdx.x - 2048);
    else     h_part<false>(x, W, vtS, t_s, blockIdx.x - 2048);
  }
}

// ---------------- Kernel 1b: src/dst projections -> rank-1 softmax factors ----------
// p'_ij = adj * max(F_j, R_i*H_j), R=exp(-0.8*src), F=exp(dst), H=exp(0.2*dst).
template<bool F32> DEV void k_sd_body(const unsigned short* __restrict__ vtS,
                                      const void* __restrict__ a_src, const void* __restrict__ a_dst,
                                      unsigned int* __restrict__ rvh,
                                      unsigned short* __restrict__ Fh,
                                      unsigned short* __restrict__ Hh) {
  const int t = blockIdx.x * 256 + threadIdx.x;      // (bh, n), n fastest
  const int n = t & 2047, bh = t >> 11, hh = bh & 3;
  const unsigned short* colp = vtS + ((size_t)(bh * 2) * 64 + (n >> 5)) * 512
                             + ((n >> 3) & 3) * 128 + (n & 7);
  float s = 0.f, d = 0.f;
#pragma unroll
  for (int dd = 0; dd < 32; ++dd) {
    const float v = (float)__builtin_bit_cast(_Float16,
                      colp[(dd >> 4) * 32768 + (dd & 15) * 8]);
    s += v * ldS<F32>(a_src, hh * 32 + dd);
    d += v * ldS<F32>(a_dst, hh * 32 + dd);
  }
  const float R = nexp2(-0.8f * LOG2E * s);
  const float F = nexp2(LOG2E * d);
  const float H = nexp2(0.2f * LOG2E * d);
  rvh[t] = pk_f16(R, R);                             // broadcast f16 pair
  Fh[t] = f_to_f16(F);
  Hh[t] = f_to_f16(H);
}
__global__ __launch_bounds__(256) void k_sd(const unsigned short* vtS, const void* a_src,
                                            const void* a_dst, unsigned int* rvh,
                                            unsigned short* Fh, unsigned short* Hh,
                                            const void* adj) {
  if (detect_f32(adj)) k_sd_body<true>(vtS, a_src, a_dst, rvh, Fh, Hh);
  else                 k_sd_body<false>(vtS, a_src, a_dst, rvh, Fh, Hh);
}

// ---------------- Kernel 2: f16 streaming attention, sched_barrier-pinned pipeline ---
// r10 post-mortem: depth-2 prefetch without spill was NULL -- but hipcc is free to
// SINK the prefetch loads past the compute (m99-m141: source-level pipelining is
// routinely defeated), so r10 may never have emitted the pipeline. This version pins
// it: __builtin_amdgcn_sched_barrier(0) after each pload forbids the compiler from
// moving the 6 prefetch loads below the compute body -- the emitted stream MUST be
// [6 loads issued] || [compute prev buffer]. Everything else identical to r10.
struct Pref {
  i32x4 a0, a1;    // adj f16 fragments, i-tiles 0/1
  i32x4 v0, v1;    // V^T dh=0/1 fragments
  i32x4 ff, fh;    // F, H f16 rows
};

DEV void pload(Pref& p, const unsigned short* ap0, const unsigned short* ap1,
               const unsigned short* vp0, const unsigned short* vp1,
               const unsigned short* fpF, const unsigned short* fpH, int j) {
  p.a0 = *(const i32x4*)(ap0 + j * 512);
  p.a1 = *(const i32x4*)(ap1 + j * 512);
  p.v0 = *(const i32x4*)(vp0 + j * 512);
  p.v1 = *(const i32x4*)(vp1 + j * 512);
  p.ff = *(const i32x4*)(fpF + j * 32);
  p.fh = *(const i32x4*)(fpH + j * 32);
}

DEV void pcompute(const Pref& p, const f16x8 R80, const f16x8 R81, const f16x8 ONE8,
                  f32x4 (&accA)[2], f32x4 (&accB)[2], f32x4 (&accD)[2]) {
  const f16x8 F8 = __builtin_bit_cast(f16x8, p.ff);
  const f16x8 H8 = __builtin_bit_cast(f16x8, p.fh);
  const f16x8 A0 = __builtin_bit_cast(f16x8, p.v0);
  const f16x8 A1 = __builtin_bit_cast(f16x8, p.v1);
  const f16x8 w0 = __builtin_elementwise_max(F8, R80 * H8);   // exp(leaky)/E_i
  const f16x8 p0 = __builtin_bit_cast(f16x8, p.a0) * w0;
  __builtin_amdgcn_s_setprio(1);
  accA[0] = __builtin_amdgcn_mfma_f32_16x16x32_f16(A0,   p0, accA[0], 0, 0, 0);
  accB[0] = __builtin_amdgcn_mfma_f32_16x16x32_f16(A1,   p0, accB[0], 0, 0, 0);
  accD[0] = __builtin_amdgcn_mfma_f32_16x16x32_f16(ONE8, p0, accD[0], 0, 0, 0);
  __builtin_amdgcn_s_setprio(0);
  const f16x8 w1 = __builtin_elementwise_max(F8, R81 * H8);
  const f16x8 p1 = __builtin_bit_cast(f16x8, p.a1) * w1;
  __builtin_amdgcn_s_setprio(1);
  accA[1] = __builtin_amdgcn_mfma_f32_16x16x32_f16(A0,   p1, accA[1], 0, 0, 0);
  accB[1] = __builtin_amdgcn_mfma_f32_16x16x32_f16(A1,   p1, accB[1], 0, 0, 0);
  accD[1] = __builtin_amdgcn_mfma_f32_16x16x32_f16(ONE8, p1, accD[1], 0, 0, 0);
  __builtin_amdgcn_s_setprio(0);
}

__global__ __launch_bounds__(256, 4) void k_attn(const unsigned short* __restrict__ adjS,
                                                 const unsigned short* __restrict__ vtS,
                                                 const unsigned int* __restrict__ rvh,
                                                 const unsigned short* __restrict__ Fh,
                                                 const unsigned short* __restrict__ Hh,
                                                 unsigned short* __restrict__ ao) {
  __shared__ __align__(16) float red[3072];          // 12288 B epilogue scratch
  const int tid = threadIdx.x, lane = tid & 63, wave = tid >> 6;   // wave = j-quarter
  const int bh = blockIdx.x & 31, iblk = blockIdx.x >> 5;  // natural: XCD = bh%8
  const int b = bh >> 2, hh = bh & 3;
  const int m = lane & 15, q = lane >> 4;
  const int i0 = iblk * 32;
  const int jq0 = wave * 16;                         // first j-tile (of 64) for this wave

  const unsigned short* ap0 = adjS + ((size_t)(iblk * 2    ) * 64 + jq0) * 512 + lane * 8;
  const unsigned short* ap1 = adjS + ((size_t)(iblk * 2 + 1) * 64 + jq0) * 512 + lane * 8;
  const unsigned short* vp0 = vtS + ((size_t)(bh * 2    ) * 64 + jq0) * 512 + lane * 8;
  const unsigned short* vp1 = vtS + ((size_t)(bh * 2 + 1) * 64 + jq0) * 512 + lane * 8;
  const unsigned short* fpF = Fh + (size_t)bh * 2048 + jq0 * 32 + q * 8;
  const unsigned short* fpH = Hh + (size_t)bh * 2048 + jq0 * 32 + q * 8;

  const unsigned int r0 = rvh[bh * 2048 + i0 + m];
  const unsigned int r1 = rvh[bh * 2048 + i0 + 16 + m];
  const i32x4 rb0 = {(int)r0, (int)r0, (int)r0, (int)r0};
  const i32x4 rb1 = {(int)r1, (int)r1, (int)r1, (int)r1};
  const f16x8 R80 = __builtin_bit_cast(f16x8, rb0);
  const f16x8 R81 = __builtin_bit_cast(f16x8, rb1);
  const i32x4 onev = {0x3C003C00, 0x3C003C00, 0x3C003C00, 0x3C003C00};
  const f16x8 ONE8 = __builtin_bit_cast(f16x8, onev);  // 8x f16 1.0

  f32x4 accA[2], accB[2], accD[2];
#pragma unroll
  for (int it = 0; it < 2; ++it) {
    accA[it] = f32x4{0.f,0.f,0.f,0.f};
    accB[it] = f32x4{0.f,0.f,0.f,0.f};
    accD[it] = f32x4{0.f,0.f,0.f,0.f};
  }

  // ---- depth-2 pipeline, PINNED: loads may not sink below the following compute ----
  Pref pA, pB;
  pload(pA, ap0, ap1, vp0, vp1, fpF, fpH, 0);
  __builtin_amdgcn_sched_barrier(0);
#pragma unroll
  for (int c = 0; c < 16; c += 2) {
    pload(pB, ap0, ap1, vp0, vp1, fpF, fpH, c + 1);
    __builtin_amdgcn_sched_barrier(0);               // pin: pB loads issued here
    pcompute(pA, R80, R81, ONE8, accA, accB, accD);
    __builtin_amdgcn_sched_barrier(0);
    if (c + 2 < 16) {
      pload(pA, ap0, ap1, vp0, vp1, fpF, fpH, c + 2);
      __builtin_amdgcn_sched_barrier(0);             // pin: pA loads issued here
    }
    pcompute(pB, R80, R81, ONE8, accA, accB, accD);
    __builtin_amdgcn_sched_barrier(0);
  }

  // ---- 2-round tree merge of the 4 j-quarter partials (r6-verified pattern) ----
  if (wave == 1 || wave == 3) {
    const int reg = (wave >> 1) * 1536;
#pragma unroll
    for (int it = 0; it < 2; ++it) {
      const int base = reg + (it * 64 + lane) * 12;
      *(f32x4*)&red[base]     = accA[it];
      *(f32x4*)&red[base + 4] = accB[it];
      red[base + 8] = accD[it][0];
    }
  }
  __syncthreads();
  if (wave == 0 || wave == 2) {
    const int reg = (wave >> 1) * 1536;
#pragma unroll
    for (int it = 0; it < 2; ++it) {
      const int base = reg + (it * 64 + lane) * 12;
      accA[it] += *(const f32x4*)&red[base];
      accB[it] += *(const f32x4*)&red[base + 4];
      accD[it][0] += red[base + 8];
    }
  }
  __syncthreads();
  if (wave == 2) {
#pragma unroll
    for (int it = 0; it < 2; ++it) {
      const int base = (it * 64 + lane) * 12;
      *(f32x4*)&red[base]     = accA[it];
      *(f32x4*)&red[base + 4] = accB[it];
      red[base + 8] = accD[it][0];
    }
  }
  __syncthreads();
  if (wave == 0) {
#pragma unroll
    for (int it = 0; it < 2; ++it) {
      const int base = (it * 64 + lane) * 12;
      const f32x4 a0 = accA[it] + *(const f32x4*)&red[base];
      const f32x4 a1 = accB[it] + *(const f32x4*)&red[base + 4];
      const float den = accD[it][0] + red[base + 8];
      const float inv = 1.f / fmaxf(den, 1e-20f);
      const int il = it * 16 + m;
      // D: col = m = i, row = q*4+r = d. Lane writes channels q*4..+3 and 16+q*4..+3.
      unsigned short* op = ao + ((size_t)(b * 2048) + i0 + il) * 128 + hh * 32 + q * 4;
      u32x2 w0, w1;
      w0[0] = pack_bf_rne(a0[0] * inv, a0[1] * inv);
      w0[1] = pack_bf_rne(a0[2] * inv, a0[3] * inv);
      w1[0] = pack_bf_rne(a1[0] * inv, a1[1] * inv);
      w1[1] = pack_bf_rne(a1[2] * inv, a1[3] * inv);
      *(u32x2*)op        = w0;
      *(u32x2*)(op + 16) = w1;
    }
  }
}

// ---------------- Kernel 3: y = LN(ao @ Wo^T + bo + x) ----------------
template<bool F32> DEV void k_out_body(const unsigned short* __restrict__ ao,
                                       const void* __restrict__ Wo, const void* __restrict__ bo,
                                       const void* __restrict__ x, const void* __restrict__ gamma,
                                       const void* __restrict__ beta, void* __restrict__ out,
                                       float (&y_s)[16][132]) {
  const int tid = threadIdx.x, lane = tid & 63, wave = tid >> 6;
  const int m = lane & 15, q = lane >> 4;
  const int rbase = blockIdx.x * 16;
  bf16x8 af[4];
#pragma unroll
  for (int k = 0; k < 4; ++k)
    af[k] = ldfrag<false>(ao, ((size_t)(rbase + m)) * 128 + q * 8 + k * 32);
  f32x4 acc[2] = {{0.f,0.f,0.f,0.f},{0.f,0.f,0.f,0.f}};
#pragma unroll
  for (int ct = 0; ct < 2; ++ct) {
    const size_t wrow = (size_t)(wave * 32 + ct * 16 + m) * 128 + q * 8;
#pragma unroll
    for (int k = 0; k < 4; ++k)
      acc[ct] = __builtin_amdgcn_mfma_f32_16x16x32_bf16(af[k], ldfrag<F32>(Wo, wrow + k * 32),
                                                        acc[ct], 0, 0, 0);
  }
#pragma unroll
  for (int ct = 0; ct < 2; ++ct) {
    const int c = wave * 32 + ct * 16 + m;
    const float bov = ldS<F32>(bo, c);
#pragma unroll
    for (int r = 0; r < 4; ++r) {
      const int row = q * 4 + r;
      y_s[row][c] = acc[ct][r] + bov + ldS<F32>(x, (size_t)(rbase + row) * 128 + c);
    }
  }
  __syncthreads();
  const int r = tid >> 4, c16 = tid & 15;
  float vals[8], sum = 0.f, sq = 0.f;
#pragma unroll
  for (int k = 0; k < 8; ++k) {
    const float v = y_s[r][c16 * 8 + k];
    vals[k] = v; sum += v; sq += v * v;
  }
#pragma unroll
  for (int msk = 1; msk < 16; msk <<= 1) {
    sum += __shfl_xor(sum, msk, 16);
    sq  += __shfl_xor(sq,  msk, 16);
  }
  const float mu  = sum * (1.f / 128.f);
  const float var = fmaxf(sq * (1.f / 128.f) - mu * mu, 0.f);
  const float rstd = rsqrtf(var + 1e-5f);
  float o[8];
#pragma unroll
  for (int k = 0; k < 8; ++k) {
    const int c = c16 * 8 + k;
    o[k] = (vals[k] - mu) * rstd * ldS<F32>(gamma, c) + ldS<F32>(beta, c);
  }
  const size_t obase = (size_t)(rbase + r) * 128 + c16 * 8;
  if constexpr (F32) {
    float* op = (float*)out + obase;
    f32x4 w0 = {o[0],o[1],o[2],o[3]}, w1 = {o[4],o[5],o[6],o[7]};
    *(f32x4*)op = w0; *(f32x4*)(op + 4) = w1;
  } else {
    union { unsigned short u[8]; i32x4 v; } ob;
#pragma unroll
    for (int k = 0; k < 8; ++k) ob.u[k] = f_to_bf(o[k]);
    *(i32x4*)((unsigned short*)out + obase) = ob.v;
  }
}
__global__ __launch_bounds__(256) void k_out(const unsigned short* ao, const void* Wo,
                                             const void* bo, const void* x, const void* gamma,
                                             const void* beta, void* out, const void* adj) {
  __shared__ __align__(16) float y_s[16][132];   // shared across both instantiations
  if (detect_f32(adj)) k_out_body<true>(ao, Wo, bo, x, gamma, beta, out, y_s);
  else                 k_out_body<false>(ao, Wo, bo, x, gamma, beta, out, y_s);
}

// ---------------- launch ----------------
extern "C" void kernel_launch(void* const* d_in, const int* in_sizes, int n_in,
                              void* d_out, int out_size, void* d_ws, size_t ws_size,
                              hipStream_t stream) {
  const void* x     = d_in[0];
  const void* adj   = d_in[1];
  const void* W     = d_in[2];
  const void* a_src = d_in[3];
  const void* a_dst = d_in[4];
  const void* Wo    = d_in[5];
  const void* bo    = d_in[6];
  const void* gamma = d_in[7];
  const void* beta  = d_in[8];

  char* ws = (char*)d_ws;
  unsigned short* adjS  = (unsigned short*)ws;               // 8,388,608 B  f16 adj, frag order
  unsigned short* vtS   = (unsigned short*)(ws + 8388608);   // 4,194,304 B  f16 V^T, frag order
  unsigned short* ao_ws = (unsigned short*)(ws + 12582912);  // 4,194,304 B  bf16 attn out
  unsigned int*   rvh   = (unsigned int*)(ws + 16777216);    //   262,144 B  f16 pair (R,R)
  unsigned short* Fh    = (unsigned short*)(ws + 17039360);  //   131,072 B  f16 F
  unsigned short* Hh    = (unsigned short*)(ws + 17170432);  //   131,072 B  f16 H
                                                             // total 17,301,504 B

  k_pre <<<3072, 256, 0, stream>>>(adj, x, W, adjS, vtS);
  k_sd  <<<256,  256, 0, stream>>>(vtS, a_src, a_dst, rvh, Fh, Hh, adj);
  k_attn<<<2048, 256, 0, stream>>>(adjS, vtS, rvh, Fh, Hh, ao_ws);
  k_out <<<1024, 256, 0, stream>>>(ao_ws, Wo, bo, x, gamma, beta, d_out, adj);
}

// Round 14
// 146.028 us; speedup vs baseline: 1.1729x; 1.0027x over previous
//
#include <hip/hip_runtime.h>

typedef short bf16x8 __attribute__((ext_vector_type(8)));   // 8 bf16 in 4 VGPRs
typedef _Float16 f16x8 __attribute__((ext_vector_type(8))); // 8 f16 in 4 VGPRs
typedef float f32x4  __attribute__((ext_vector_type(4)));
typedef float f32x2  __attribute__((ext_vector_type(2)));
typedef int   i32x4  __attribute__((ext_vector_type(4)));
typedef unsigned int u32x2 __attribute__((ext_vector_type(2)));

#define DEV static __device__ __forceinline__
#define LOG2E 1.4426950408889634f

DEV float bfu_to_f(unsigned short s) { return __builtin_bit_cast(float, (unsigned int)s << 16); }
DEV unsigned short f_to_bf(float f) {                 // RNE fp32 -> bf16
  unsigned int u = __builtin_bit_cast(unsigned int, f);
  u += 0x7fffu + ((u >> 16) & 1u);
  return (unsigned short)(u >> 16);
}
DEV unsigned int pack_bf_rne(float lo, float hi) {
  return (unsigned int)f_to_bf(lo) | ((unsigned int)f_to_bf(hi) << 16);
}
// packed f32 -> 2x f16 (single v_cvt_pkrtz_f16_f32, full rate)
DEV unsigned int pk_f16(float a, float b) {
  auto h = __builtin_amdgcn_cvt_pkrtz(a, b);
  return __builtin_bit_cast(unsigned int, h);
}
DEV unsigned short f_to_f16(float a) { return __builtin_bit_cast(unsigned short, (_Float16)a); }
// guaranteed-native exp2 (single v_exp_f32)
DEV float nexp2(float x) {
#if __has_builtin(__builtin_amdgcn_exp2f)
  return __builtin_amdgcn_exp2f(x);
#else
  return exp2f(x);
#endif
}

// dtype discriminator: adj[0][0] == 1.0 exactly. fp32 word0 == 0x3F800000;
// bf16 word0 low halfword = 0x3F80 != 0 -> never equal.
DEV bool detect_f32(const void* adj) { return ((const float*)adj)[0] == 1.0f; }

template<bool F32> DEV float ldS(const void* p, size_t i) {
  if constexpr (F32) return ((const float*)p)[i];
  else               return bfu_to_f(((const unsigned short*)p)[i]);
}
template<bool F32> DEV void ld8f(const void* p, size_t i, float* o) {
  if constexpr (F32) {
    const float* f = (const float*)p + i;
    f32x4 a = *(const f32x4*)f, b = *(const f32x4*)(f + 4);
    o[0]=a[0]; o[1]=a[1]; o[2]=a[2]; o[3]=a[3];
    o[4]=b[0]; o[5]=b[1]; o[6]=b[2]; o[7]=b[3];
  } else {
    i32x4 w = *(const i32x4*)((const unsigned short*)p + i);
#pragma unroll
    for (int k = 0; k < 4; ++k) {
      unsigned int u = (unsigned int)w[k];
      o[2*k]   = __builtin_bit_cast(float, u << 16);
      o[2*k+1] = __builtin_bit_cast(float, u & 0xffff0000u);
    }
  }
}
template<bool F32> DEV bf16x8 ldfrag(const void* p, size_t i) {
  if constexpr (F32) {
    float o[8]; ld8f<true>(p, i, o);
    union { bf16x8 v; unsigned short u[8]; } r;
#pragma unroll
    for (int k = 0; k < 8; ++k) r.u[k] = f_to_bf(o[k]);
    return r.v;
  } else {
    return __builtin_bit_cast(bf16x8, *(const i32x4*)((const unsigned short*)p + i));
  }
}

// Fragment order for a 16x32 f16 MFMA operand tile: lane l holds elements
// [row = l&15][col = (l>>4)*8 .. +7] at flat offset l*8. One tile = 512 f16 = 1 KB.
// A wave's dwordx4 load at base + lane*16B is perfectly coalesced (1 KB sequential).

// -------- Kernel 0+1 fused: adj->f16 frag order AND vtS=(x@W^T)^T frag order --------
// Blocks [0,2048): adj prep (tile T = blockIdx*4+wave). Blocks [2048,3072): k_h.
template<bool F32> DEV void prep_part(const void* __restrict__ adj,
                                      unsigned short* __restrict__ adjS, int blk) {
  const int tid = threadIdx.x, lane = tid & 63, w = tid >> 6;
  const int T = blk * 4 + w;                         // 0..8191
  const int it = T >> 6, jt = T & 63;
  const int m = lane & 15, q = lane >> 4;
  const size_t src = (size_t)(it * 16 + m) * 2048 + jt * 32 + q * 8;
  float f[8];
  ld8f<F32>(adj, src, f);
  i32x4 o;
#pragma unroll
  for (int k = 0; k < 4; ++k) o[k] = (int)pk_f16(f[2*k], f[2*k+1]);
  *(i32x4*)(adjS + (size_t)T * 512 + lane * 8) = o;
}
template<bool F32> DEV void h_part(const void* __restrict__ x, const void* __restrict__ W,
                                   unsigned short* __restrict__ vtS,
                                   unsigned short (&t_s)[16][136], int blk) {
  const int tid = threadIdx.x, lane = tid & 63, wave = tid >> 6;
  const int nt = blk >> 3, ct = blk & 7;             // 128 nt x 8 ct
  const int m = lane & 15, q = lane >> 4;
  bf16x8 wf[4];
#pragma unroll
  for (int k = 0; k < 4; ++k)
    wf[k] = ldfrag<F32>(W, (size_t)(ct * 16 + m) * 128 + q * 8 + k * 32);
#pragma unroll
  for (int s = 0; s < 2; ++s) {
    const int nsub = wave * 2 + s;
    const size_t xr = (size_t)(nt * 128 + nsub * 16 + m) * 128 + q * 8;
    f32x4 acc = {0.f, 0.f, 0.f, 0.f};
#pragma unroll
    for (int k = 0; k < 4; ++k)
      acc = __builtin_amdgcn_mfma_f32_16x16x32_bf16(ldfrag<F32>(x, xr + k * 32), wf[k],
                                                    acc, 0, 0, 0);
    u32x2 w2; w2[0] = pack_bf_rne(acc[0], acc[1]); w2[1] = pack_bf_rne(acc[2], acc[3]);
    *(u32x2*)&t_s[m][nsub * 16 + q * 4] = w2;
  }
  __syncthreads();
  const int row = tid >> 4, c8 = tid & 15;
  const int chg = ct * 16 + row, hh = chg >> 5, dloc = chg & 31;
  const int ng = nt * 128 + c8 * 8, b = ng >> 11, nl = ng & 2047;
  i32x4 v = *(const i32x4*)&t_s[row][c8 * 8];       // 8 bf16
  float f[8];
#pragma unroll
  for (int k = 0; k < 4; ++k) {
    unsigned int u = (unsigned int)v[k];
    f[2*k]   = __builtin_bit_cast(float, u << 16);
    f[2*k+1] = __builtin_bit_cast(float, u & 0xffff0000u);
  }
  i32x4 o;
#pragma unroll
  for (int k = 0; k < 4; ++k) o[k] = (int)pk_f16(f[2*k], f[2*k+1]);
  const int bh_ = b * 4 + hh;
  const size_t idx = ((size_t)(bh_ * 2 + (dloc >> 4)) * 64 + (nl >> 5)) * 512
                   + (((nl >> 3) & 3) * 16 + (dloc & 15)) * 8;
  *(i32x4*)(vtS + idx) = o;
}
__global__ __launch_bounds__(256) void k_pre(const void* adj, const void* x, const void* W,
                                             unsigned short* adjS, unsigned short* vtS) {
  __shared__ __align__(16) unsigned short t_s[16][136];
  const bool f32 = detect_f32(adj);
  if (blockIdx.x < 2048) {
    if (f32) prep_part<true>(adj, adjS, blockIdx.x);
    else     prep_part<false>(adj, adjS, blockIdx.x);
  } else {
    if (f32) h_part<true>(x, W, vtS, t_s, blockIdx.x - 2048);
    else     h_part<false>(x, W, vtS, t_s, blockIdx.x - 2048);
  }
}

// ---------------- Kernel 1b: src/dst projections -> rank-1 softmax factors ----------
// p'_ij = adj * max(F_j, R_i*H_j), R=exp(-0.8*src), F=exp(dst), H=exp(0.2*dst).
template<bool F32> DEV void k_sd_body(const unsigned short* __restrict__ vtS,
                                      const void* __restrict__ a_src, const void* __restrict__ a_dst,
                                      unsigned int* __restrict__ rvh,
                                      unsigned short* __restrict__ Fh,
                                      unsigned short* __restrict__ Hh) {
  const int t = blockIdx.x * 256 + threadIdx.x;      // (bh, n), n fastest
  const int n = t & 2047, bh = t >> 11, hh = bh & 3;
  const unsigned short* colp = vtS + ((size_t)(bh * 2) * 64 + (n >> 5)) * 512
                             + ((n >> 3) & 3) * 128 + (n & 7);
  float s = 0.f, d = 0.f;
#pragma unroll
  for (int dd = 0; dd < 32; ++dd) {
    const float v = (float)__builtin_bit_cast(_Float16,
                      colp[(dd >> 4) * 32768 + (dd & 15) * 8]);
    s += v * ldS<F32>(a_src, hh * 32 + dd);
    d += v * ldS<F32>(a_dst, hh * 32 + dd);
  }
  const float R = nexp2(-0.8f * LOG2E * s);
  const float F = nexp2(LOG2E * d);
  const float H = nexp2(0.2f * LOG2E * d);
  rvh[t] = pk_f16(R, R);                             // broadcast f16 pair
  Fh[t] = f_to_f16(F);
  Hh[t] = f_to_f16(H);
}
__global__ __launch_bounds__(256) void k_sd(const unsigned short* vtS, const void* a_src,
                                            const void* a_dst, unsigned int* rvh,
                                            unsigned short* Fh, unsigned short* Hh,
                                            const void* adj) {
  if (detect_f32(adj)) k_sd_body<true>(vtS, a_src, a_dst, rvh, Fh, Hh);
  else                 k_sd_body<false>(vtS, a_src, a_dst, rvh, Fh, Hh);
}

// ------- Kernel 2: f16 streaming attention, pinned pipeline, UNCAPPED registers -----
// r11 post-mortem: every capture with launch_bounds(256,4) shows VGPR_Count pinned at
// EXACTLY 64 + scratch writes (r4: 9MB, r7: 60MB, r9: 67MB vs 4MB expected) -> the
// bounds imposed a hard 64-VGPR cap (8-waves/SIMD tier) and every structure needing
// more SPILLED. r10/r11's depth-2 pipeline (acc 24 + Pref 48 + addr ~30 = ~100 regs)
// ran with ~36 regs in scratch -- the latency theory was never tested. One change:
// __launch_bounds__(256, 1) -> compiler allocates ~110 regs (128-tier = 4 waves/SIMD,
// same occupancy target), zero spill, pipeline finally lives in registers.
// (r12: container died twice; r13: GPU acquisition timeout -- identical resubmission.)
struct Pref {
  i32x4 a0, a1;    // adj f16 fragments, i-tiles 0/1
  i32x4 v0, v1;    // V^T dh=0/1 fragments
  i32x4 ff, fh;    // F, H f16 rows
};

DEV void pload(Pref& p, const unsigned short* ap0, const unsigned short* ap1,
               const unsigned short* vp0, const unsigned short* vp1,
               const unsigned short* fpF, const unsigned short* fpH, int j) {
  p.a0 = *(const i32x4*)(ap0 + j * 512);
  p.a1 = *(const i32x4*)(ap1 + j * 512);
  p.v0 = *(const i32x4*)(vp0 + j * 512);
  p.v1 = *(const i32x4*)(vp1 + j * 512);
  p.ff = *(const i32x4*)(fpF + j * 32);
  p.fh = *(const i32x4*)(fpH + j * 32);
}

DEV void pcompute(const Pref& p, const f16x8 R80, const f16x8 R81, const f16x8 ONE8,
                  f32x4 (&accA)[2], f32x4 (&accB)[2], f32x4 (&accD)[2]) {
  const f16x8 F8 = __builtin_bit_cast(f16x8, p.ff);
  const f16x8 H8 = __builtin_bit_cast(f16x8, p.fh);
  const f16x8 A0 = __builtin_bit_cast(f16x8, p.v0);
  const f16x8 A1 = __builtin_bit_cast(f16x8, p.v1);
  const f16x8 w0 = __builtin_elementwise_max(F8, R80 * H8);   // exp(leaky)/E_i
  const f16x8 p0 = __builtin_bit_cast(f16x8, p.a0) * w0;
  __builtin_amdgcn_s_setprio(1);
  accA[0] = __builtin_amdgcn_mfma_f32_16x16x32_f16(A0,   p0, accA[0], 0, 0, 0);
  accB[0] = __builtin_amdgcn_mfma_f32_16x16x32_f16(A1,   p0, accB[0], 0, 0, 0);
  accD[0] = __builtin_amdgcn_mfma_f32_16x16x32_f16(ONE8, p0, accD[0], 0, 0, 0);
  __builtin_amdgcn_s_setprio(0);
  const f16x8 w1 = __builtin_elementwise_max(F8, R81 * H8);
  const f16x8 p1 = __builtin_bit_cast(f16x8, p.a1) * w1;
  __builtin_amdgcn_s_setprio(1);
  accA[1] = __builtin_amdgcn_mfma_f32_16x16x32_f16(A0,   p1, accA[1], 0, 0, 0);
  accB[1] = __builtin_amdgcn_mfma_f32_16x16x32_f16(A1,   p1, accB[1], 0, 0, 0);
  accD[1] = __builtin_amdgcn_mfma_f32_16x16x32_f16(ONE8, p1, accD[1], 0, 0, 0);
  __builtin_amdgcn_s_setprio(0);
}

__global__ __launch_bounds__(256, 1) void k_attn(const unsigned short* __restrict__ adjS,
                                                 const unsigned short* __restrict__ vtS,
                                                 const unsigned int* __restrict__ rvh,
                                                 const unsigned short* __restrict__ Fh,
                                                 const unsigned short* __restrict__ Hh,
                                                 unsigned short* __restrict__ ao) {
  __shared__ __align__(16) float red[3072];          // 12288 B epilogue scratch
  const int tid = threadIdx.x, lane = tid & 63, wave = tid >> 6;   // wave = j-quarter
  const int bh = blockIdx.x & 31, iblk = blockIdx.x >> 5;  // natural: XCD = bh%8
  const int b = bh >> 2, hh = bh & 3;
  const int m = lane & 15, q = lane >> 4;
  const int i0 = iblk * 32;
  const int jq0 = wave * 16;                         // first j-tile (of 64) for this wave

  const unsigned short* ap0 = adjS + ((size_t)(iblk * 2    ) * 64 + jq0) * 512 + lane * 8;
  const unsigned short* ap1 = adjS + ((size_t)(iblk * 2 + 1) * 64 + jq0) * 512 + lane * 8;
  const unsigned short* vp0 = vtS + ((size_t)(bh * 2    ) * 64 + jq0) * 512 + lane * 8;
  const unsigned short* vp1 = vtS + ((size_t)(bh * 2 + 1) * 64 + jq0) * 512 + lane * 8;
  const unsigned short* fpF = Fh + (size_t)bh * 2048 + jq0 * 32 + q * 8;
  const unsigned short* fpH = Hh + (size_t)bh * 2048 + jq0 * 32 + q * 8;

  const unsigned int r0 = rvh[bh * 2048 + i0 + m];
  const unsigned int r1 = rvh[bh * 2048 + i0 + 16 + m];
  const i32x4 rb0 = {(int)r0, (int)r0, (int)r0, (int)r0};
  const i32x4 rb1 = {(int)r1, (int)r1, (int)r1, (int)r1};
  const f16x8 R80 = __builtin_bit_cast(f16x8, rb0);
  const f16x8 R81 = __builtin_bit_cast(f16x8, rb1);
  const i32x4 onev = {0x3C003C00, 0x3C003C00, 0x3C003C00, 0x3C003C00};
  const f16x8 ONE8 = __builtin_bit_cast(f16x8, onev);  // 8x f16 1.0

  f32x4 accA[2], accB[2], accD[2];
#pragma unroll
  for (int it = 0; it < 2; ++it) {
    accA[it] = f32x4{0.f,0.f,0.f,0.f};
    accB[it] = f32x4{0.f,0.f,0.f,0.f};
    accD[it] = f32x4{0.f,0.f,0.f,0.f};
  }

  // ---- depth-2 pipeline, PINNED: loads may not sink below the following compute ----
  Pref pA, pB;
  pload(pA, ap0, ap1, vp0, vp1, fpF, fpH, 0);
  __builtin_amdgcn_sched_barrier(0);
#pragma unroll
  for (int c = 0; c < 16; c += 2) {
    pload(pB, ap0, ap1, vp0, vp1, fpF, fpH, c + 1);
    __builtin_amdgcn_sched_barrier(0);               // pin: pB loads issued here
    pcompute(pA, R80, R81, ONE8, accA, accB, accD);
    __builtin_amdgcn_sched_barrier(0);
    if (c + 2 < 16) {
      pload(pA, ap0, ap1, vp0, vp1, fpF, fpH, c + 2);
      __builtin_amdgcn_sched_barrier(0);             // pin: pA loads issued here
    }
    pcompute(pB, R80, R81, ONE8, accA, accB, accD);
    __builtin_amdgcn_sched_barrier(0);
  }

  // ---- 2-round tree merge of the 4 j-quarter partials (r6-verified pattern) ----
  if (wave == 1 || wave == 3) {
    const int reg = (wave >> 1) * 1536;
#pragma unroll
    for (int it = 0; it < 2; ++it) {
      const int base = reg + (it * 64 + lane) * 12;
      *(f32x4*)&red[base]     = accA[it];
      *(f32x4*)&red[base + 4] = accB[it];
      red[base + 8] = accD[it][0];
    }
  }
  __syncthreads();
  if (wave == 0 || wave == 2) {
    const int reg = (wave >> 1) * 1536;
#pragma unroll
    for (int it = 0; it < 2; ++it) {
      const int base = reg + (it * 64 + lane) * 12;
      accA[it] += *(const f32x4*)&red[base];
      accB[it] += *(const f32x4*)&red[base + 4];
      accD[it][0] += red[base + 8];
    }
  }
  __syncthreads();
  if (wave == 2) {
#pragma unroll
    for (int it = 0; it < 2; ++it) {
      const int base = (it * 64 + lane) * 12;
      *(f32x4*)&red[base]     = accA[it];
      *(f32x4*)&red[base + 4] = accB[it];
      red[base + 8] = accD[it][0];
    }
  }
  __syncthreads();
  if (wave == 0) {
#pragma unroll
    for (int it = 0; it < 2; ++it) {
      const int base = (it * 64 + lane) * 12;
      const f32x4 a0 = accA[it] + *(const f32x4*)&red[base];
      const f32x4 a1 = accB[it] + *(const f32x4*)&red[base + 4];
      const float den = accD[it][0] + red[base + 8];
      const float inv = 1.f / fmaxf(den, 1e-20f);
      const int il = it * 16 + m;
      // D: col = m = i, row = q*4+r = d. Lane writes channels q*4..+3 and 16+q*4..+3.
      unsigned short* op = ao + ((size_t)(b * 2048) + i0 + il) * 128 + hh * 32 + q * 4;
      u32x2 w0, w1;
      w0[0] = pack_bf_rne(a0[0] * inv, a0[1] * inv);
      w0[1] = pack_bf_rne(a0[2] * inv, a0[3] * inv);
      w1[0] = pack_bf_rne(a1[0] * inv, a1[1] * inv);
      w1[1] = pack_bf_rne(a1[2] * inv, a1[3] * inv);
      *(u32x2*)op        = w0;
      *(u32x2*)(op + 16) = w1;
    }
  }
}

// ---------------- Kernel 3: y = LN(ao @ Wo^T + bo + x) ----------------
template<bool F32> DEV void k_out_body(const unsigned short* __restrict__ ao,
                                       const void* __restrict__ Wo, const void* __restrict__ bo,
                                       const void* __restrict__ x, const void* __restrict__ gamma,
                                       const void* __restrict__ beta, void* __restrict__ out,
                                       float (&y_s)[16][132]) {
  const int tid = threadIdx.x, lane = tid & 63, wave = tid >> 6;
  const int m = lane & 15, q = lane >> 4;
  const int rbase = blockIdx.x * 16;
  bf16x8 af[4];
#pragma unroll
  for (int k = 0; k < 4; ++k)
    af[k] = ldfrag<false>(ao, ((size_t)(rbase + m)) * 128 + q * 8 + k * 32);
  f32x4 acc[2] = {{0.f,0.f,0.f,0.f},{0.f,0.f,0.f,0.f}};
#pragma unroll
  for (int ct = 0; ct < 2; ++ct) {
    const size_t wrow = (size_t)(wave * 32 + ct * 16 + m) * 128 + q * 8;
#pragma unroll
    for (int k = 0; k < 4; ++k)
      acc[ct] = __builtin_amdgcn_mfma_f32_16x16x32_bf16(af[k], ldfrag<F32>(Wo, wrow + k * 32),
                                                        acc[ct], 0, 0, 0);
  }
#pragma unroll
  for (int ct = 0; ct < 2; ++ct) {
    const int c = wave * 32 + ct * 16 + m;
    const float bov = ldS<F32>(bo, c);
#pragma unroll
    for (int r = 0; r < 4; ++r) {
      const int row = q * 4 + r;
      y_s[row][c] = acc[ct][r] + bov + ldS<F32>(x, (size_t)(rbase + row) * 128 + c);
    }
  }
  __syncthreads();
  const int r = tid >> 4, c16 = tid & 15;
  float vals[8], sum = 0.f, sq = 0.f;
#pragma unroll
  for (int k = 0; k < 8; ++k) {
    const float v = y_s[r][c16 * 8 + k];
    vals[k] = v; sum += v; sq += v * v;
  }
#pragma unroll
  for (int msk = 1; msk < 16; msk <<= 1) {
    sum += __shfl_xor(sum, msk, 16);
    sq  += __shfl_xor(sq,  msk, 16);
  }
  const float mu  = sum * (1.f / 128.f);
  const float var = fmaxf(sq * (1.f / 128.f) - mu * mu, 0.f);
  const float rstd = rsqrtf(var + 1e-5f);
  float o[8];
#pragma unroll
  for (int k = 0; k < 8; ++k) {
    const int c = c16 * 8 + k;
    o[k] = (vals[k] - mu) * rstd * ldS<F32>(gamma, c) + ldS<F32>(beta, c);
  }
  const size_t obase = (size_t)(rbase + r) * 128 + c16 * 8;
  if constexpr (F32) {
    float* op = (float*)out + obase;
    f32x4 w0 = {o[0],o[1],o[2],o[3]}, w1 = {o[4],o[5],o[6],o[7]};
    *(f32x4*)op = w0; *(f32x4*)(op + 4) = w1;
  } else {
    union { unsigned short u[8]; i32x4 v; } ob;
#pragma unroll
    for (int k = 0; k < 8; ++k) ob.u[k] = f_to_bf(o[k]);
    *(i32x4*)((unsigned short*)out + obase) = ob.v;
  }
}
__global__ __launch_bounds__(256) void k_out(const unsigned short* ao, const void* Wo,
                                             const void* bo, const void* x, const void* gamma,
                                             const void* beta, void* out, const void* adj) {
  __shared__ __align__(16) float y_s[16][132];   // shared across both instantiations
  if (detect_f32(adj)) k_out_body<true>(ao, Wo, bo, x, gamma, beta, out, y_s);
  else                 k_out_body<false>(ao, Wo, bo, x, gamma, beta, out, y_s);
}

// ---------------- launch ----------------
extern "C" void kernel_launch(void* const* d_in, const int* in_sizes, int n_in,
                              void* d_out, int out_size, void* d_ws, size_t ws_size,
                              hipStream_t stream) {
  const void* x     = d_in[0];
  const void* adj   = d_in[1];
  const void* W     = d_in[2];
  const void* a_src = d_in[3];
  const void* a_dst = d_in[4];
  const void* Wo    = d_in[5];
  const void* bo    = d_in[6];
  const void* gamma = d_in[7];
  const void* beta  = d_in[8];

  char* ws = (char*)d_ws;
  unsigned short* adjS  = (unsigned short*)ws;               // 8,388,608 B  f16 adj, frag order
  unsigned short* vtS   = (unsigned short*)(ws + 8388608);   // 4,194,304 B  f16 V^T, frag order
  unsigned short* ao_ws = (unsigned short*)(ws + 12582912);  // 4,194,304 B  bf16 attn out
  unsigned int*   rvh   = (unsigned int*)(ws + 16777216);    //   262,144 B  f16 pair (R,R)
  unsigned short* Fh    = (unsigned short*)(ws + 17039360);  //   131,072 B  f16 F
  unsigned short* Hh    = (unsigned short*)(ws + 17170432);  //   131,072 B  f16 H
                                                             // total 17,301,504 B

  k_pre <<<3072, 256, 0, stream>>>(adj, x, W, adjS, vtS);
  k_sd  <<<256,  256, 0, stream>>>(vtS, a_src, a_dst, rvh, Fh, Hh, adj);
  k_attn<<<2048, 256, 0, stream>>>(adjS, vtS, rvh, Fh, Hh, ao_ws);
  k_out <<<1024, 256, 0, stream>>>(ao_ws, Wo, bo, x, gamma, beta, d_out, adj);
}